// Round 4
// baseline (278.489 us; speedup 1.0000x reference)
//
#include <hip/hip_runtime.h>

#define B_DIM 4
#define T_DIM 4096
#define C_DIM 2048
#define KK 4
#define C4 (C_DIM / 4)   // 512 float4 groups per row

typedef float v4f __attribute__((ext_vector_type(4)));

// One thread per output float4. 4 independent tap loads (contiguous shifted
// streams; 3/4 are L2 hits from neighbor blocks' primary loads) feed one FMA
// chain + one nontemporal store. No intra-thread recurrence -> compiler must
// batch all loads before the first waitcnt -> guaranteed MLP.
__global__ __launch_bounds__(256) void canonconv_kernel(
    const float* __restrict__ x,
    const float* __restrict__ w,
    const float* __restrict__ bias,
    float* __restrict__ out)
{
    const int i4  = blockIdx.x * blockDim.x + threadIdx.x; // global float4 index
    const int c4  = i4 & (C4 - 1);       // channel group
    const int row = i4 >> 9;             // b*T_DIM + t   (C4 = 512 = 2^9)
    const int t   = row & (T_DIM - 1);   // wave-uniform (64 lanes span 1/8 row)
    const int c   = c4 * 4;

    const v4f* xv = (const v4f*)x;

    // clamped offsets: safe addresses even at t<3 (contribution masked below)
    const int o1 = (t >= 1) ? (i4 - 1 * C4) : i4;
    const int o2 = (t >= 2) ? (i4 - 2 * C4) : i4;
    const int o3 = (t >= 3) ? (i4 - 3 * C4) : i4;

    // all independent -> issued back-to-back
    const v4f x0  = xv[i4];   // x[t]
    const v4f xm1 = xv[o1];   // x[t-1]
    const v4f xm2 = xv[o2];   // x[t-2]
    const v4f xm3 = xv[o3];   // x[t-3]

    const v4f* wv = (const v4f*)(w + (size_t)c * KK);
    v4f a0 = wv[0];   // (w[c+0,0..3])
    v4f a1 = wv[1];
    v4f a2 = wv[2];
    v4f a3 = wv[3];
    const v4f bv = *(const v4f*)(bias + c);

    // boundary masks (wave-uniform selects)
    const float m1 = (t >= 1) ? 1.0f : 0.0f;
    const float m2 = (t >= 2) ? 1.0f : 0.0f;
    const float m3 = (t >= 3) ? 1.0f : 0.0f;

    v4f r;
    // channel c+0 uses a0 = (w0,w1,w2,w3): taps on x[t-3],x[t-2],x[t-1],x[t]
    r.x = fmaf(x0.x, 1.0f + a0.w,
          fmaf(xm1.x, m1 * a0.z,
          fmaf(xm2.x, m2 * a0.y,
          fmaf(xm3.x, m3 * a0.x, bv.x))));
    r.y = fmaf(x0.y, 1.0f + a1.w,
          fmaf(xm1.y, m1 * a1.z,
          fmaf(xm2.y, m2 * a1.y,
          fmaf(xm3.y, m3 * a1.x, bv.y))));
    r.z = fmaf(x0.z, 1.0f + a2.w,
          fmaf(xm1.z, m1 * a2.z,
          fmaf(xm2.z, m2 * a2.y,
          fmaf(xm3.z, m3 * a2.x, bv.z))));
    r.w = fmaf(x0.w, 1.0f + a3.w,
          fmaf(xm1.w, m1 * a3.z,
          fmaf(xm2.w, m2 * a3.y,
          fmaf(xm3.w, m3 * a3.x, bv.w))));

    __builtin_nontemporal_store(r, ((v4f*)out) + i4);
}

extern "C" void kernel_launch(void* const* d_in, const int* in_sizes, int n_in,
                              void* d_out, int out_size, void* d_ws, size_t ws_size,
                              hipStream_t stream) {
    const float* x    = (const float*)d_in[0];
    const float* w    = (const float*)d_in[1];
    const float* bias = (const float*)d_in[2];
    float* out = (float*)d_out;

    const int total_threads = B_DIM * T_DIM * C4; // 4*4096*512 = 8388608
    const int block = 256;
    const int grid  = total_threads / block;      // 32768
    canonconv_kernel<<<grid, block, 0, stream>>>(x, w, bias, out);
}